// Round 26
// baseline (143.954 us; speedup 1.0000x reference)
//
#include <hip/hip_runtime.h>

// 2-layer tanh RNN, fused, f32. R26 = R25's 2-wave phased split, REBALANCED
// via a z-ring: h1[t] = tanh(z[t] + W_hh1 h1[t-1]), z[t] = W_ih1 h0[t] + b1.
//  - wave0: layer0 recurrence (3 dots, serial) + z[t-1] (3 dots on the SAME
//    h0[t-1] broadcast it already read -- pure stall-filler) -> writes z
//    to a 32-slot ring. h0 state is wave0-private (no ring needed).
//  - wave1: 3 scalar z reads + own h1 read -> 3 dots -> add -> tanh.
//    Chain and issue both ~halved vs R25 (was the straggler at 6 dots).
//  - wave1 lags TWO phases (z of phase p complete only during wave0 phase
//    p+1). Ring-distance writer-reader in [7,22] mod 32 -> race-free.
//    wave0 gets a z-epilogue phase (k==NPH) for z[511].
//  - waves_per_eu(1,1) residency (R24); 512 blocks x 2 waves = 1024 waves
//    = exactly 1/SIMD (R24's cap lesson). GB=8, 8 lanes/batch, 3 row-slots
//    (jj, jj+8, clamped jj+16; dup lanes write identical values: benign).

#define Bsz 4096
#define Tn  512
#define Hn  20
#define GB  8
#define K   8
#define ZR  32                 // z-ring slots (4 phases)
#define NPH (Tn / K)           // 64
#define XPAD 516
#define NTHREADS 128

typedef float v2 __attribute__((ext_vector_type(2)));

__device__ __forceinline__ float tanh_fast(float v) {
    // tanh(v) = 1 - 2/(exp(2v)+1); v_exp_f32 + v_rcp_f32.
    float e = __expf(2.0f * v);
    return 1.0f - 2.0f * __builtin_amdgcn_rcpf(e + 1.0f);
}

// packed 20-dot: 10 v_pk_fma_f32, two chains
#define DOT20P(acc, accb, W, H) do { \
    acc  = __builtin_elementwise_fma(W##0, H##0, acc);  \
    accb = __builtin_elementwise_fma(W##1, H##1, accb); \
    acc  = __builtin_elementwise_fma(W##2, H##2, acc);  \
    accb = __builtin_elementwise_fma(W##3, H##3, accb); \
    acc  = __builtin_elementwise_fma(W##4, H##4, acc);  \
    accb = __builtin_elementwise_fma(W##5, H##5, accb); \
    acc  = __builtin_elementwise_fma(W##6, H##6, acc);  \
    accb = __builtin_elementwise_fma(W##7, H##7, accb); \
    acc  = __builtin_elementwise_fma(W##8, H##8, acc);  \
    accb = __builtin_elementwise_fma(W##9, H##9, accb); \
} while (0)

#define LOAD_ROWP(W, ptr) \
    v2 W##0, W##1, W##2, W##3, W##4, W##5, W##6, W##7, W##8, W##9; \
    { const float4* _p = (const float4*)(ptr); \
      float4 _t; \
      _t = _p[0]; W##0 = (v2){_t.x, _t.y}; W##1 = (v2){_t.z, _t.w}; \
      _t = _p[1]; W##2 = (v2){_t.x, _t.y}; W##3 = (v2){_t.z, _t.w}; \
      _t = _p[2]; W##4 = (v2){_t.x, _t.y}; W##5 = (v2){_t.z, _t.w}; \
      _t = _p[3]; W##6 = (v2){_t.x, _t.y}; W##7 = (v2){_t.z, _t.w}; \
      _t = _p[4]; W##8 = (v2){_t.x, _t.y}; W##9 = (v2){_t.z, _t.w}; }

#define READ_H(H, base) \
    v2 H##0, H##1, H##2, H##3, H##4, H##5, H##6, H##7, H##8, H##9; \
    { const float4 _a = *(const float4*)((base) + 0);  \
      const float4 _b = *(const float4*)((base) + 4);  \
      const float4 _c = *(const float4*)((base) + 8);  \
      const float4 _d = *(const float4*)((base) + 12); \
      const float4 _e = *(const float4*)((base) + 16); \
      H##0 = (v2){_a.x, _a.y}; H##1 = (v2){_a.z, _a.w}; \
      H##2 = (v2){_b.x, _b.y}; H##3 = (v2){_b.z, _b.w}; \
      H##4 = (v2){_c.x, _c.y}; H##5 = (v2){_c.z, _c.w}; \
      H##6 = (v2){_d.x, _d.y}; H##7 = (v2){_d.z, _d.w}; \
      H##8 = (v2){_e.x, _e.y}; H##9 = (v2){_e.z, _e.w}; }

__global__ __launch_bounds__(NTHREADS)
__attribute__((amdgpu_waves_per_eu(1, 1)))
void rnn2_fused(const float* __restrict__ x,        // [B,T,1]
                const float* __restrict__ hidden,   // [2,B,H]
                const float* __restrict__ W_ih0,    // [H,1]
                const float* __restrict__ W_hh0,    // [H,H]
                const float* __restrict__ b_ih0,    // [H]
                const float* __restrict__ b_hh0,    // [H]
                const float* __restrict__ W_ih1,    // [H,H]
                const float* __restrict__ W_hh1,    // [H,H]
                const float* __restrict__ b_ih1,    // [H]
                const float* __restrict__ b_hh1,    // [H]
                const float* __restrict__ fc_w,     // [1,H]
                const float* __restrict__ fc_b,     // [1]
                float* __restrict__ out)            // [B] ++ [2,B,H] flat
{
    const int tid  = threadIdx.x;
    const int wave = tid >> 6;         // 0 = layer0+z producer, 1 = layer1
    const int lane = tid & 63;
    const int g    = lane >> 3;        // batch 0..7
    const int jj   = lane & 7;         // 0..7
    const int r0   = jj;
    const int r1   = jj + 8;
    const int r2   = (jj + 16 < Hn) ? (jj + 16) : (Hn - 1);  // clamped dup
    const int b    = blockIdx.x * GB + g;   // 4096 = 512*8: always valid

    __shared__ float xs[GB][XPAD];     // 16.5 KB (wave0 only reads)
    __shared__ float zr[ZR][GB][Hn];   // z ring, 20.5 KB (cross-wave)
    __shared__ float h0s[GB][Hn];      // wave0-private
    __shared__ float h1s[GB][Hn];      // wave1-private

    // wave0: wA = W_hh0 rows (h0 dots), wZ = W_ih1 rows (z dots).
    // wave1: wZ = W_hh1 rows (c dots); wA unused.
    const float* mZ = (wave == 0) ? W_ih1 : W_hh1;
    LOAD_ROWP(wA0, W_hh0 + r0 * Hn)
    LOAD_ROWP(wA1, W_hh0 + r1 * Hn)
    LOAD_ROWP(wA2, W_hh0 + r2 * Hn)
    LOAD_ROWP(wZ0, mZ + r0 * Hn)
    LOAD_ROWP(wZ1, mZ + r1 * Hn)
    LOAD_ROWP(wZ2, mZ + r2 * Hn)

    const float wih0_0 = W_ih0[r0], wih0_1 = W_ih0[r1], wih0_2 = W_ih0[r2];
    const float bA0 = b_ih0[r0] + b_hh0[r0];   // layer0 bias (wave0)
    const float bA1 = b_ih0[r1] + b_hh0[r1];
    const float bA2 = b_ih0[r2] + b_hh0[r2];
    const float bZ0 = b_ih1[r0] + b_hh1[r0];   // layer1 bias (into z, wave0)
    const float bZ1 = b_ih1[r1] + b_hh1[r1];
    const float bZ2 = b_ih1[r2] + b_hh1[r2];

    // ---- stage ALL x (128 threads, coalesced float4)
    {
        const int bB = blockIdx.x * GB;
        #pragma unroll
        for (int r = 0; r < (GB * Tn) / (NTHREADS * 4); ++r) {  // 8 rounds
            const int c  = (r * NTHREADS + tid) * 4;
            const int gg = c >> 9;
            const int t  = c & (Tn - 1);
            float4 v = *(const float4*)(x + (long)(bB + gg) * Tn + t);
            *(float4*)&xs[gg][t] = v;
        }
    }

    // ---- init: h0[-1] -> h0s (wave0); h1[-1] -> h1s (wave1)
    if (wave == 0) {
        h0s[g][r0] = hidden[(long)b * Hn + r0];
        h0s[g][r1] = hidden[(long)b * Hn + r1];
        h0s[g][r2] = hidden[(long)b * Hn + r2];   // dup benign
    } else {
        h1s[g][r0] = hidden[(long)Bsz * Hn + (long)b * Hn + r0];
        h1s[g][r1] = hidden[(long)Bsz * Hn + (long)b * Hn + r1];
        h1s[g][r2] = hidden[(long)Bsz * Hn + (long)b * Hn + r2];
    }
    __syncthreads();

    float k0 = 0.f, k1 = 0.f, k2 = 0.f;   // last computed per slot

    // ---- phases k=0..NPH+1 (66):
    //  wave0: k<NPH -> steps t=kK..kK+7: h0[t] + z[t-1]; k==NPH -> z[511].
    //  wave1: 2<=k<=NPH+1 -> steps t=(k-2)K..(k-2)K+7: h1[t] from z[t]+c.
    for (int k = 0; k <= NPH + 1; ++k) {
        if (wave == 0) {
            if (k < NPH) {
                #pragma unroll
                for (int u = 0; u < K; ++u) {
                    const int t = k * K + u;
                    READ_H(hA, &h0s[g][0])          // h0[t-1]
                    const float xt = xs[g][t];
                    v2 a0 = (v2){fmaf(xt, wih0_0, bA0), 0.f}, a0b = (v2){0.f, 0.f};
                    v2 a1 = (v2){fmaf(xt, wih0_1, bA1), 0.f}, a1b = (v2){0.f, 0.f};
                    v2 a2 = (v2){fmaf(xt, wih0_2, bA2), 0.f}, a2b = (v2){0.f, 0.f};
                    v2 z0 = (v2){bZ0, 0.f}, z0b = (v2){0.f, 0.f};
                    v2 z1 = (v2){bZ1, 0.f}, z1b = (v2){0.f, 0.f};
                    v2 z2 = (v2){bZ2, 0.f}, z2b = (v2){0.f, 0.f};
                    DOT20P(a0, a0b, wA0, hA);       // serial layer0
                    DOT20P(a1, a1b, wA1, hA);
                    DOT20P(a2, a2b, wA2, hA);
                    DOT20P(z0, z0b, wZ0, hA);       // z[t-1]: independent filler
                    DOT20P(z1, z1b, wZ1, hA);
                    DOT20P(z2, z2b, wZ2, hA);
                    const v2 s0 = a0 + a0b, s1 = a1 + a1b, s2 = a2 + a2b;
                    k0 = tanh_fast(s0.x + s0.y);
                    k1 = tanh_fast(s1.x + s1.y);
                    k2 = tanh_fast(s2.x + s2.y);
                    h0s[g][r0] = k0;                // h0[t]
                    h0s[g][r1] = k1;
                    h0s[g][r2] = k2;                // dup benign
                    const v2 t0 = z0 + z0b, t1 = z1 + z1b, t2 = z2 + z2b;
                    const int zq = (t - 1) & (ZR - 1);
                    zr[zq][g][r0] = t0.x + t0.y;    // z[t-1] (t=0: unused slot)
                    zr[zq][g][r1] = t1.x + t1.y;
                    zr[zq][g][r2] = t2.x + t2.y;
                }
            } else if (k == NPH) {
                // z-epilogue: z[511] from h0[511]
                READ_H(hA, &h0s[g][0])
                v2 z0 = (v2){bZ0, 0.f}, z0b = (v2){0.f, 0.f};
                v2 z1 = (v2){bZ1, 0.f}, z1b = (v2){0.f, 0.f};
                v2 z2 = (v2){bZ2, 0.f}, z2b = (v2){0.f, 0.f};
                DOT20P(z0, z0b, wZ0, hA);
                DOT20P(z1, z1b, wZ1, hA);
                DOT20P(z2, z2b, wZ2, hA);
                const v2 t0 = z0 + z0b, t1 = z1 + z1b, t2 = z2 + z2b;
                const int zq = (Tn - 1) & (ZR - 1);   // 511 & 31 = 31
                zr[zq][g][r0] = t0.x + t0.y;
                zr[zq][g][r1] = t1.x + t1.y;
                zr[zq][g][r2] = t2.x + t2.y;
            }
        } else {
            if (k >= 2) {
                #pragma unroll
                for (int u = 0; u < K; ++u) {
                    const int t = (k - 2) * K + u;
                    const int zq = t & (ZR - 1);
                    const float zv0 = zr[zq][g][r0];   // z[t] (pre-phase)
                    const float zv1 = zr[zq][g][r1];
                    const float zv2 = zr[zq][g][r2];
                    READ_H(hB, &h1s[g][0])             // h1[t-1] (own)
                    v2 c0 = (v2){0.f, 0.f}, c0b = (v2){0.f, 0.f};
                    v2 c1 = (v2){0.f, 0.f}, c1b = (v2){0.f, 0.f};
                    v2 c2 = (v2){0.f, 0.f}, c2b = (v2){0.f, 0.f};
                    DOT20P(c0, c0b, wZ0, hB);          // W_hh1 rows
                    DOT20P(c1, c1b, wZ1, hB);
                    DOT20P(c2, c2b, wZ2, hB);
                    const v2 s0 = c0 + c0b, s1 = c1 + c1b, s2 = c2 + c2b;
                    k0 = tanh_fast(zv0 + s0.x + s0.y);
                    k1 = tanh_fast(zv1 + s1.x + s1.y);
                    k2 = tanh_fast(zv2 + s2.x + s2.y);
                    h1s[g][r0] = k0;                   // h1[t]
                    h1s[g][r1] = k1;
                    h1s[g][r2] = k2;                   // dup benign
                }
            }
        }
        if (k <= NPH) __syncthreads();   // uniform; publishes z writes
    }

    // ---- outputs (k0/k1/k2 hold step-511 values)
    if (wave == 0) {
        out[Bsz + (long)b * Hn + r0] = k0;                    // new_hidden[0]
        out[Bsz + (long)b * Hn + r1] = k1;
        out[Bsz + (long)b * Hn + r2] = k2;                    // dup benign
    } else {
        out[Bsz + (long)Bsz * Hn + (long)b * Hn + r0] = k0;   // new_hidden[1]
        out[Bsz + (long)Bsz * Hn + (long)b * Hn + r1] = k1;
        out[Bsz + (long)Bsz * Hn + (long)b * Hn + r2] = k2;
        if (jj == 0) {                 // fc head: one lane per batch
            LOAD_ROWP(fw, fc_w)
            READ_H(hv, &h1s[g][0])     // own-wave in-order
            v2 aA = (v2){fc_b[0], 0.f};
            v2 aB = (v2){0.f, 0.f};
            DOT20P(aA, aB, fw, hv);
            const v2 s = aA + aB;
            out[b] = s.x + s.y;
        }
    }
}

extern "C" void kernel_launch(void* const* d_in, const int* in_sizes, int n_in,
                              void* d_out, int out_size, void* d_ws, size_t ws_size,
                              hipStream_t stream) {
    const float* x      = (const float*)d_in[0];
    const float* hidden = (const float*)d_in[1];
    const float* W_ih0  = (const float*)d_in[2];
    const float* W_hh0  = (const float*)d_in[3];
    const float* b_ih0  = (const float*)d_in[4];
    const float* b_hh0  = (const float*)d_in[5];
    const float* W_ih1  = (const float*)d_in[6];
    const float* W_hh1  = (const float*)d_in[7];
    const float* b_ih1  = (const float*)d_in[8];
    const float* b_hh1  = (const float*)d_in[9];
    const float* fc_w   = (const float*)d_in[10];
    const float* fc_b   = (const float*)d_in[11];

    rnn2_fused<<<Bsz / GB, NTHREADS, 0, stream>>>(   // 512 blocks = 1024 waves
        x, hidden, W_ih0, W_hh0, b_ih0, b_hh0,
        W_ih1, W_hh1, b_ih1, b_hh1, fc_w, fc_b, (float*)d_out);
}